// Round 5
// baseline (205.616 us; speedup 1.0000x reference)
//
#include <hip/hip_runtime.h>
#include <hip/hip_bf16.h>
#include <cstddef>

namespace {
constexpr int B  = 2;
constexpr int Z  = 200;
constexpr int X  = 200;
constexpr int C  = 128;
constexpr int H  = 4;
constexpr int P  = 8;
constexpr int N  = Z * X;       // 40000
constexpr int BN = B * N;       // 80000
constexpr int SC = 96;          // proj_s cols: 64 offsets (f32) + 32 softmax'd weights (f32)
constexpr int NF_P = 14;        // 224/16 output fragments (proj GEMM)
constexpr int NF_O = 8;         // 128/16 output fragments (out GEMM)
constexpr int KS   = 4;         // 128/32 K-steps

typedef __attribute__((ext_vector_type(8))) short short8;
typedef __attribute__((ext_vector_type(4))) float f32x4;

__device__ inline ushort f2bf(float x) {
    __hip_bfloat16 h = __float2bfloat16(x);
    return *reinterpret_cast<ushort*>(&h);
}
__device__ inline float bflo(unsigned u) { return __uint_as_float(u << 16); }
__device__ inline float bfhi(unsigned u) { return __uint_as_float(u & 0xffff0000u); }
__device__ inline unsigned packbf(float a, float b) {
    return (unsigned)f2bf(a) | ((unsigned)f2bf(b) << 16);
}
// single-instruction lane xor-shuffles (BitMode ds_swizzle), masks 1/2/4
template <int MASK>
__device__ inline float swzx(float x) {
    constexpr int pat = (MASK << 10) | 0x1F;
    return __int_as_float(__builtin_amdgcn_ds_swizzle(__float_as_int(x), pat));
}
}

// ---------------------------------------------------------------------------
// Prep: pack weights into MFMA B-fragment order wt[ks][f][lane][8 bf16],
// k = ks*32 + (l>>4)*8 + e, n = f*16 + (l&15). Also folds W12 = Wout1@Wout2,
// biasp[224], b12[128].
// ---------------------------------------------------------------------------
__global__ __launch_bounds__(256) void vsa_k_prep(
    const float* __restrict__ Wv,    const float* __restrict__ bv,
    const float* __restrict__ Woff,  const float* __restrict__ boff,
    const float* __restrict__ Wattn, const float* __restrict__ battn,
    const float* __restrict__ Wout1, const float* __restrict__ bout1,
    const float* __restrict__ Wout2, const float* __restrict__ bout2,
    ushort* __restrict__ wtp, ushort* __restrict__ wtp2,
    float* __restrict__ biasp, float* __restrict__ bias2)
{
    const int u = blockIdx.x * 256 + threadIdx.x;
    constexpr int NP = KS * NF_P * 64;   // 3584
    constexpr int NO = KS * NF_O * 64;   // 2048

    if (u < NP) {
        int ks  = u / (NF_P * 64);
        int rem = u - ks * (NF_P * 64);
        int f = rem >> 6, l = rem & 63;
        int n  = f * 16 + (l & 15);
        int kb = ks * 32 + (l >> 4) * 8;
        float v[8];
        #pragma unroll
        for (int e = 0; e < 8; ++e) {
            int k = kb + e;
            if (n < 128)      v[e] = Wv[k * 128 + n];
            else if (n < 192) v[e] = Woff[k * 64 + (n - 128)];
            else              v[e] = Wattn[k * 32 + (n - 192)];
        }
        unsigned* dst = (unsigned*)(wtp + (size_t)u * 8);
        #pragma unroll
        for (int i = 0; i < 4; ++i) dst[i] = packbf(v[2*i], v[2*i+1]);
    } else if (u < NP + NO) {
        int t   = u - NP;
        int ks  = t / (NF_O * 64);
        int rem = t - ks * (NF_O * 64);
        int f = rem >> 6, l = rem & 63;
        int n  = f * 16 + (l & 15);
        int kb = ks * 32 + (l >> 4) * 8;
        float acc[8] = {0,0,0,0,0,0,0,0};
        for (int j = 0; j < 128; ++j) {
            float w2 = Wout2[j * 128 + n];
            #pragma unroll
            for (int e = 0; e < 8; ++e)
                acc[e] = fmaf(Wout1[(kb + e) * 128 + j], w2, acc[e]);
        }
        unsigned* dst = (unsigned*)(wtp2 + (size_t)t * 8);
        #pragma unroll
        for (int i = 0; i < 4; ++i) dst[i] = packbf(acc[2*i], acc[2*i+1]);
    } else if (u < NP + NO + 224) {
        int c = u - NP - NO;
        float bb;
        if (c < 128)      bb = bv[c];
        else if (c < 192) bb = boff[c - 128];
        else              bb = battn[c - 192];
        biasp[c] = bb;
    } else if (u < NP + NO + 224 + 128) {
        int c = u - NP - NO - 224;
        float acc = bout2[c];
        for (int j = 0; j < 128; ++j)
            acc = fmaf(bout1[j], Wout2[j * 128 + c], acc);
        bias2[c] = acc;
    }
}

// ---------------------------------------------------------------------------
// Fused projection GEMM (MFMA, no LDS) + softmax epilogue.
//   cols 0..127   -> proj_v (bf16 values)
//   cols 128..191 -> proj_s[row][0..63]  (f32 offsets)
//   cols 192..223 -> softmax over each 8-point group (lanes m&7 via xor
//                    ds_swizzle 1/2/4) -> proj_s[row][64..95] (f32 weights)
// ---------------------------------------------------------------------------
__global__ __launch_bounds__(256) void vsa_k_proj(
    const float* __restrict__ Q, const ushort* __restrict__ wtp,
    const float* __restrict__ biasp,
    ushort* __restrict__ proj_v, float* __restrict__ proj_s)
{
    const int lane = threadIdx.x & 63;
    const int wave = blockIdx.x * 4 + (threadIdx.x >> 6);
    const int row0 = wave * 16;
    const int m  = lane & 15;
    const int kg = lane >> 4;

    const float* qp = Q + (size_t)(row0 + m) * 128 + kg * 8;

    f32x4 acc[NF_P];
    #pragma unroll
    for (int f = 0; f < NF_P; ++f) acc[f] = (f32x4){0.f, 0.f, 0.f, 0.f};

    #pragma unroll
    for (int ks = 0; ks < KS; ++ks) {
        float4 a0 = *(const float4*)(qp + ks * 32);
        float4 a1 = *(const float4*)(qp + ks * 32 + 4);
        short8 af;
        af[0] = (short)f2bf(a0.x); af[1] = (short)f2bf(a0.y);
        af[2] = (short)f2bf(a0.z); af[3] = (short)f2bf(a0.w);
        af[4] = (short)f2bf(a1.x); af[5] = (short)f2bf(a1.y);
        af[6] = (short)f2bf(a1.z); af[7] = (short)f2bf(a1.w);
        const short8* wrow = (const short8*)wtp + ks * NF_P * 64 + lane;
        #pragma unroll
        for (int f = 0; f < NF_P; ++f)
            acc[f] = __builtin_amdgcn_mfma_f32_16x16x32_bf16(af, wrow[f * 64], acc[f], 0, 0, 0);
    }

    // values -> bf16
    #pragma unroll
    for (int f = 0; f < 8; ++f) {
        const int col = f * 16 + m;
        const float bb = biasp[col];
        #pragma unroll
        for (int r = 0; r < 4; ++r)
            proj_v[(size_t)(row0 + kg * 4 + r) * 128 + col] = f2bf(acc[f][r] + bb);
    }
    // offsets -> f32
    #pragma unroll
    for (int f = 8; f < 12; ++f) {
        const int col = f * 16 + m;
        const float bb = biasp[col];
        #pragma unroll
        for (int r = 0; r < 4; ++r)
            proj_s[(size_t)(row0 + kg * 4 + r) * SC + (col - 128)] = acc[f][r] + bb;
    }
    // attn logits -> softmax -> f32 weights
    #pragma unroll
    for (int f = 12; f < 14; ++f) {
        const float bb = biasp[f * 16 + m];
        #pragma unroll
        for (int r = 0; r < 4; ++r) {
            float v = acc[f][r] + bb;
            float mx = v;
            mx = fmaxf(mx, swzx<1>(mx));
            mx = fmaxf(mx, swzx<2>(mx));
            mx = fmaxf(mx, swzx<4>(mx));
            float ex = __expf(v - mx);
            float sm = ex;
            sm += swzx<1>(sm); sm += swzx<2>(sm); sm += swzx<4>(sm);
            const float wp = ex / sm;
            proj_s[(size_t)(row0 + kg * 4 + r) * SC + 64 + (f - 12) * 16 + m] = wp;
        }
    }
}

// ---------------------------------------------------------------------------
// Deformable sampling: one wave per (b, n, h) — 320k waves for latency hiding
// (empirically proven rate in round 2), wave id WITHIN the block = head, so
// the 4 heads of a pixel share value-row cache lines in L1/L2.
// lane = d4*8 + p: p = point (bits 0..2 -> xor-swizzle 1/2/4 reduce),
// d4 = 4 head-dim elems (uint2 = 4 bf16, coalesced 64B per point-group).
// Grid (200,200,2): i = blockIdx.x (gather-fast dim), j = blockIdx.y, b = z.
// No divisions, no softmax (precomputed by vsa_k_proj).
// ---------------------------------------------------------------------------
__global__ __launch_bounds__(256) void vsa_k_sample(
    const ushort* __restrict__ proj_v, const float* __restrict__ proj_s,
    ushort* __restrict__ tmp)
{
    const int lane = threadIdx.x & 63;
    const int h    = threadIdx.x >> 6;     // wave id = head
    const int p  = lane & 7;
    const int d4 = lane >> 3;              // 0..7

    const int i = blockIdx.x;              // gather rows adjacent along i
    const int j = blockIdx.y;
    const int b = blockIdx.z;
    const size_t bn = (size_t)b * N + i * X + j;

    const float* srow = proj_s + bn * SC;
    const char*  vb   = (const char*)(proj_v + (size_t)b * N * 128);

    // per-lane point data (issued first, off the critical path)
    const float2 off = *(const float2*)(srow + (h * 8 + p) * 2);
    const float  wp  = srow[64 + h * 8 + p];

    const float ixf = (float)i + off.x;
    const float iyf = (float)j + off.y;
    const float x0f = floorf(ixf), y0f = floorf(iyf);
    const float lx = ixf - x0f, ly = iyf - y0f;
    const int x0 = (int)x0f, y0 = (int)y0f;
    const int x1 = x0 + 1,  y1 = y0 + 1;
    const int xc0 = min(max(x0, 0), X - 1), xc1 = min(max(x1, 0), X - 1);
    const int yc0 = min(max(y0, 0), Z - 1), yc1 = min(max(y1, 0), Z - 1);

    const float wx0 = ((unsigned)x0 < (unsigned)X) ? (1.f - lx) : 0.f;
    const float wx1 = ((unsigned)x1 < (unsigned)X) ? lx : 0.f;
    const float wy0 = (((unsigned)y0 < (unsigned)Z) ? (1.f - ly) : 0.f) * wp;
    const float wy1 = (((unsigned)y1 < (unsigned)Z) ? ly : 0.f) * wp;
    const float w00 = wx0 * wy0, w10 = wx1 * wy0;
    const float w01 = wx0 * wy1, w11 = wx1 * wy1;

    const int rb0 = yc0 * X, rb1 = yc1 * X;
    const int hb  = h * 64 + d4 * 8;

    const uint2 c00 = *(const uint2*)(vb + (rb0 + xc0) * 256 + hb);
    const uint2 c10 = *(const uint2*)(vb + (rb0 + xc1) * 256 + hb);
    const uint2 c01 = *(const uint2*)(vb + (rb1 + xc0) * 256 + hb);
    const uint2 c11 = *(const uint2*)(vb + (rb1 + xc1) * 256 + hb);

    float a0 = w00*bflo(c00.x) + w10*bflo(c10.x) + w01*bflo(c01.x) + w11*bflo(c11.x);
    float a1 = w00*bfhi(c00.x) + w10*bfhi(c10.x) + w01*bfhi(c01.x) + w11*bfhi(c11.x);
    float a2 = w00*bflo(c00.y) + w10*bflo(c10.y) + w01*bflo(c01.y) + w11*bflo(c11.y);
    float a3 = w00*bfhi(c00.y) + w10*bfhi(c10.y) + w01*bfhi(c01.y) + w11*bfhi(c11.y);

    // reduce over the 8 points (p = lane bits 0..2), batched stages
    a0 += swzx<1>(a0); a1 += swzx<1>(a1); a2 += swzx<1>(a2); a3 += swzx<1>(a3);
    a0 += swzx<2>(a0); a1 += swzx<2>(a1); a2 += swzx<2>(a2); a3 += swzx<2>(a3);
    a0 += swzx<4>(a0); a1 += swzx<4>(a1); a2 += swzx<4>(a2); a3 += swzx<4>(a3);

    if (p == 0) {
        uint2 o;
        o.x = packbf(a0, a1);
        o.y = packbf(a2, a3);
        *(uint2*)(tmp + bn * 128 + h * 32 + d4 * 4) = o;
    }
}

// ---------------------------------------------------------------------------
// Output GEMM (MFMA, no LDS) + residual: out = tmp @ W12 + b12 + Q.
// ---------------------------------------------------------------------------
__global__ __launch_bounds__(256) void vsa_k_out(
    const ushort* __restrict__ tmp, const ushort* __restrict__ wtp2,
    const float* __restrict__ bias2, const float* __restrict__ Q,
    float* __restrict__ out)
{
    const int lane = threadIdx.x & 63;
    const int wave = blockIdx.x * 4 + (threadIdx.x >> 6);
    const int row0 = wave * 16;
    const int m  = lane & 15;
    const int kg = lane >> 4;

    const ushort* ap = tmp + (size_t)(row0 + m) * 128 + kg * 8;

    f32x4 acc[NF_O];
    #pragma unroll
    for (int f = 0; f < NF_O; ++f) acc[f] = (f32x4){0.f, 0.f, 0.f, 0.f};

    #pragma unroll
    for (int ks = 0; ks < KS; ++ks) {
        short8 af = *(const short8*)(ap + ks * 32);
        const short8* wrow = (const short8*)wtp2 + ks * NF_O * 64 + lane;
        #pragma unroll
        for (int f = 0; f < NF_O; ++f)
            acc[f] = __builtin_amdgcn_mfma_f32_16x16x32_bf16(af, wrow[f * 64], acc[f], 0, 0, 0);
    }

    #pragma unroll
    for (int f = 0; f < NF_O; ++f) {
        const int col = f * 16 + m;
        const float bb = bias2[col];
        #pragma unroll
        for (int r = 0; r < 4; ++r) {
            const int row = row0 + kg * 4 + r;
            out[(size_t)row * 128 + col] = acc[f][r] + bb + Q[(size_t)row * 128 + col];
        }
    }
}

// ---------------------------------------------------------------------------
extern "C" void kernel_launch(void* const* d_in, const int* in_sizes, int n_in,
                              void* d_out, int out_size, void* d_ws, size_t ws_size,
                              hipStream_t stream) {
    const float* Q     = (const float*)d_in[0];
    const float* Wv    = (const float*)d_in[1];
    const float* bv    = (const float*)d_in[2];
    const float* Woff  = (const float*)d_in[3];
    const float* boff  = (const float*)d_in[4];
    const float* Wattn = (const float*)d_in[5];
    const float* battn = (const float*)d_in[6];
    const float* Wout1 = (const float*)d_in[7];
    const float* bout1 = (const float*)d_in[8];
    const float* Wout2 = (const float*)d_in[9];
    const float* bout2 = (const float*)d_in[10];
    float* out = (float*)d_out;

    // Workspace: proj_s f32[BN][96] | biasp[224] | b12[128] |
    //            proj_v bf16[BN][128] | tmp bf16[BN][128] | wtp | wtp2
    float*  proj_s = (float*)d_ws;
    float*  biasp  = proj_s + (size_t)BN * SC;
    float*  bias2  = biasp + 224;
    ushort* proj_v = (ushort*)(bias2 + 128);
    ushort* tmp    = proj_v + (size_t)BN * 128;
    ushort* wtp    = tmp + (size_t)BN * 128;
    ushort* wtp2   = wtp + (size_t)KS * NF_P * 64 * 8;

    constexpr int prep_n = KS * NF_P * 64 + KS * NF_O * 64 + 224 + 128; // 5984
    vsa_k_prep<<<(prep_n + 255) / 256, 256, 0, stream>>>(
        Wv, bv, Woff, boff, Wattn, battn, Wout1, bout1, Wout2, bout2,
        wtp, wtp2, biasp, bias2);
    vsa_k_proj<<<BN / 64, 256, 0, stream>>>(Q, wtp, biasp, proj_v, proj_s);
    vsa_k_sample<<<dim3(Z, X, B), 256, 0, stream>>>(proj_v, proj_s, tmp);
    vsa_k_out<<<BN / 64, 256, 0, stream>>>(tmp, wtp2, bias2, Q, out);
}

// Round 6
// 123.833 us; speedup vs baseline: 1.6604x; 1.6604x over previous
//
#include <hip/hip_runtime.h>
#include <hip/hip_bf16.h>
#include <cstddef>

namespace {
constexpr int B  = 2;
constexpr int Z  = 200;
constexpr int X  = 200;
constexpr int C  = 128;
constexpr int H  = 4;
constexpr int P  = 8;
constexpr int N  = Z * X;       // 40000
constexpr int BN = B * N;       // 80000
constexpr int SC = 96;          // proj_s cols: 64 offsets (f32) + 32 softmax'd weights (f32)
constexpr int NF_P = 14;        // 224/16 output fragments (proj GEMM)
constexpr int NF_O = 8;         // 128/16 output fragments (out GEMM)
constexpr int KS   = 4;         // 128/32 K-steps

typedef __attribute__((ext_vector_type(8))) short short8;
typedef __attribute__((ext_vector_type(4))) float f32x4;

__device__ inline ushort f2bf(float x) {
    __hip_bfloat16 h = __float2bfloat16(x);
    return *reinterpret_cast<ushort*>(&h);
}
__device__ inline float bflo(unsigned u) { return __uint_as_float(u << 16); }
__device__ inline float bfhi(unsigned u) { return __uint_as_float(u & 0xffff0000u); }
__device__ inline unsigned packbf(float a, float b) {
    return (unsigned)f2bf(a) | ((unsigned)f2bf(b) << 16);
}
// single-instruction lane xor-shuffles (BitMode ds_swizzle), within 32-lane groups
template <int MASK>
__device__ inline float swzx(float x) {
    constexpr int pat = (MASK << 10) | 0x1F;
    return __int_as_float(__builtin_amdgcn_ds_swizzle(__float_as_int(x), pat));
}
}

// ---------------------------------------------------------------------------
// Prep: pack weights into MFMA B-fragment order wt[ks][f][lane][8 bf16],
// k = ks*32 + (l>>4)*8 + e, n = f*16 + (l&15). Also folds W12 = Wout1@Wout2,
// biasp[224], b12[128].
// ---------------------------------------------------------------------------
__global__ __launch_bounds__(256) void vsa_k_prep(
    const float* __restrict__ Wv,    const float* __restrict__ bv,
    const float* __restrict__ Woff,  const float* __restrict__ boff,
    const float* __restrict__ Wattn, const float* __restrict__ battn,
    const float* __restrict__ Wout1, const float* __restrict__ bout1,
    const float* __restrict__ Wout2, const float* __restrict__ bout2,
    ushort* __restrict__ wtp, ushort* __restrict__ wtp2,
    float* __restrict__ biasp, float* __restrict__ bias2)
{
    const int u = blockIdx.x * 256 + threadIdx.x;
    constexpr int NP = KS * NF_P * 64;   // 3584
    constexpr int NO = KS * NF_O * 64;   // 2048

    if (u < NP) {
        int ks  = u / (NF_P * 64);
        int rem = u - ks * (NF_P * 64);
        int f = rem >> 6, l = rem & 63;
        int n  = f * 16 + (l & 15);
        int kb = ks * 32 + (l >> 4) * 8;
        float v[8];
        #pragma unroll
        for (int e = 0; e < 8; ++e) {
            int k = kb + e;
            if (n < 128)      v[e] = Wv[k * 128 + n];
            else if (n < 192) v[e] = Woff[k * 64 + (n - 128)];
            else              v[e] = Wattn[k * 32 + (n - 192)];
        }
        unsigned* dst = (unsigned*)(wtp + (size_t)u * 8);
        #pragma unroll
        for (int i = 0; i < 4; ++i) dst[i] = packbf(v[2*i], v[2*i+1]);
    } else if (u < NP + NO) {
        int t   = u - NP;
        int ks  = t / (NF_O * 64);
        int rem = t - ks * (NF_O * 64);
        int f = rem >> 6, l = rem & 63;
        int n  = f * 16 + (l & 15);
        int kb = ks * 32 + (l >> 4) * 8;
        float acc[8] = {0,0,0,0,0,0,0,0};
        for (int j = 0; j < 128; ++j) {
            float w2 = Wout2[j * 128 + n];
            #pragma unroll
            for (int e = 0; e < 8; ++e)
                acc[e] = fmaf(Wout1[(kb + e) * 128 + j], w2, acc[e]);
        }
        unsigned* dst = (unsigned*)(wtp2 + (size_t)t * 8);
        #pragma unroll
        for (int i = 0; i < 4; ++i) dst[i] = packbf(acc[2*i], acc[2*i+1]);
    } else if (u < NP + NO + 224) {
        int c = u - NP - NO;
        float bb;
        if (c < 128)      bb = bv[c];
        else if (c < 192) bb = boff[c - 128];
        else              bb = battn[c - 192];
        biasp[c] = bb;
    } else if (u < NP + NO + 224 + 128) {
        int c = u - NP - NO - 224;
        float acc = bout2[c];
        for (int j = 0; j < 128; ++j)
            acc = fmaf(bout1[j], Wout2[j * 128 + c], acc);
        bias2[c] = acc;
    }
}

// ---------------------------------------------------------------------------
// Fused projection GEMM (MFMA, no LDS) + softmax epilogue.
//   cols 0..127   -> proj_v (bf16 values)
//   cols 128..191 -> proj_s[row][0..63]  (f32 offsets)
//   cols 192..223 -> softmax over each 8-point group (lanes m&7 via xor
//                    ds_swizzle 1/2/4) -> proj_s[row][64..95] (f32 weights)
// ---------------------------------------------------------------------------
__global__ __launch_bounds__(256) void vsa_k_proj(
    const float* __restrict__ Q, const ushort* __restrict__ wtp,
    const float* __restrict__ biasp,
    ushort* __restrict__ proj_v, float* __restrict__ proj_s)
{
    const int lane = threadIdx.x & 63;
    const int wave = blockIdx.x * 4 + (threadIdx.x >> 6);
    const int row0 = wave * 16;
    const int m  = lane & 15;
    const int kg = lane >> 4;

    const float* qp = Q + (size_t)(row0 + m) * 128 + kg * 8;

    f32x4 acc[NF_P];
    #pragma unroll
    for (int f = 0; f < NF_P; ++f) acc[f] = (f32x4){0.f, 0.f, 0.f, 0.f};

    #pragma unroll
    for (int ks = 0; ks < KS; ++ks) {
        float4 a0 = *(const float4*)(qp + ks * 32);
        float4 a1 = *(const float4*)(qp + ks * 32 + 4);
        short8 af;
        af[0] = (short)f2bf(a0.x); af[1] = (short)f2bf(a0.y);
        af[2] = (short)f2bf(a0.z); af[3] = (short)f2bf(a0.w);
        af[4] = (short)f2bf(a1.x); af[5] = (short)f2bf(a1.y);
        af[6] = (short)f2bf(a1.z); af[7] = (short)f2bf(a1.w);
        const short8* wrow = (const short8*)wtp + ks * NF_P * 64 + lane;
        #pragma unroll
        for (int f = 0; f < NF_P; ++f)
            acc[f] = __builtin_amdgcn_mfma_f32_16x16x32_bf16(af, wrow[f * 64], acc[f], 0, 0, 0);
    }

    // values -> bf16
    #pragma unroll
    for (int f = 0; f < 8; ++f) {
        const int col = f * 16 + m;
        const float bb = biasp[col];
        #pragma unroll
        for (int r = 0; r < 4; ++r)
            proj_v[(size_t)(row0 + kg * 4 + r) * 128 + col] = f2bf(acc[f][r] + bb);
    }
    // offsets -> f32
    #pragma unroll
    for (int f = 8; f < 12; ++f) {
        const int col = f * 16 + m;
        const float bb = biasp[col];
        #pragma unroll
        for (int r = 0; r < 4; ++r)
            proj_s[(size_t)(row0 + kg * 4 + r) * SC + (col - 128)] = acc[f][r] + bb;
    }
    // attn logits -> softmax -> f32 weights
    #pragma unroll
    for (int f = 12; f < 14; ++f) {
        const float bb = biasp[f * 16 + m];
        #pragma unroll
        for (int r = 0; r < 4; ++r) {
            float v = acc[f][r] + bb;
            float mx = v;
            mx = fmaxf(mx, swzx<1>(mx));
            mx = fmaxf(mx, swzx<2>(mx));
            mx = fmaxf(mx, swzx<4>(mx));
            float ex = __expf(v - mx);
            float sm = ex;
            sm += swzx<1>(sm); sm += swzx<2>(sm); sm += swzx<4>(sm);
            const float wp = ex / sm;
            proj_s[(size_t)(row0 + kg * 4 + r) * SC + 64 + (f - 12) * 16 + m] = wp;
        }
    }
}

// ---------------------------------------------------------------------------
// Deformable sampling: one wave per (b, n, h), wave id in block = head.
// LANE MAP (the round-2 fast one): d4 = lane&7 (LOW bits -> each 8-lane
// point-group reads 64 CONTIGUOUS bytes per gather -> coalesced requests),
// p = lane>>3 (bits 3..5). Reduce over p: ds_swizzle xor 8/16 + shfl_xor 32.
// Grid (200,200,2): i = blockIdx.x (gather-fast dim), j = blockIdx.y, b = z.
// No divisions, no softmax (precomputed by vsa_k_proj).
// ---------------------------------------------------------------------------
__global__ __launch_bounds__(256) void vsa_k_sample(
    const ushort* __restrict__ proj_v, const float* __restrict__ proj_s,
    ushort* __restrict__ tmp)
{
    const int lane = threadIdx.x & 63;
    const int h    = threadIdx.x >> 6;     // wave id = head
    const int p  = lane >> 3;              // point in bits 3..5
    const int d4 = lane & 7;               // head-dim quad in bits 0..2

    const int i = blockIdx.x;              // gather rows adjacent along i
    const int j = blockIdx.y;
    const int b = blockIdx.z;
    const size_t bn = (size_t)b * N + i * X + j;

    const float* srow = proj_s + bn * SC;
    const char*  vb   = (const char*)(proj_v + (size_t)b * N * 128);

    // per-point data (broadcast across the 8 d4 lanes of the group)
    const float2 off = *(const float2*)(srow + (h * 8 + p) * 2);
    const float  wp  = srow[64 + h * 8 + p];

    const float ixf = (float)i + off.x;
    const float iyf = (float)j + off.y;
    const float x0f = floorf(ixf), y0f = floorf(iyf);
    const float lx = ixf - x0f, ly = iyf - y0f;
    const int x0 = (int)x0f, y0 = (int)y0f;
    const int x1 = x0 + 1,  y1 = y0 + 1;
    const int xc0 = min(max(x0, 0), X - 1), xc1 = min(max(x1, 0), X - 1);
    const int yc0 = min(max(y0, 0), Z - 1), yc1 = min(max(y1, 0), Z - 1);

    const float wx0 = ((unsigned)x0 < (unsigned)X) ? (1.f - lx) : 0.f;
    const float wx1 = ((unsigned)x1 < (unsigned)X) ? lx : 0.f;
    const float wy0 = (((unsigned)y0 < (unsigned)Z) ? (1.f - ly) : 0.f) * wp;
    const float wy1 = (((unsigned)y1 < (unsigned)Z) ? ly : 0.f) * wp;
    const float w00 = wx0 * wy0, w10 = wx1 * wy0;
    const float w01 = wx0 * wy1, w11 = wx1 * wy1;

    const int rb0 = yc0 * X, rb1 = yc1 * X;
    const int hb  = h * 64 + d4 * 8;       // d4 contiguous: 8 lanes = 64B

    const uint2 c00 = *(const uint2*)(vb + (rb0 + xc0) * 256 + hb);
    const uint2 c10 = *(const uint2*)(vb + (rb0 + xc1) * 256 + hb);
    const uint2 c01 = *(const uint2*)(vb + (rb1 + xc0) * 256 + hb);
    const uint2 c11 = *(const uint2*)(vb + (rb1 + xc1) * 256 + hb);

    float a0 = w00*bflo(c00.x) + w10*bflo(c10.x) + w01*bflo(c01.x) + w11*bflo(c11.x);
    float a1 = w00*bfhi(c00.x) + w10*bfhi(c10.x) + w01*bfhi(c01.x) + w11*bfhi(c11.x);
    float a2 = w00*bflo(c00.y) + w10*bflo(c10.y) + w01*bflo(c01.y) + w11*bflo(c11.y);
    float a3 = w00*bfhi(c00.y) + w10*bfhi(c10.y) + w01*bfhi(c01.y) + w11*bfhi(c11.y);

    // reduce over the 8 points (p = lane bits 3..5): xor 8, 16 in-group,
    // then one cross-32 exchange
    a0 += swzx<8>(a0);  a1 += swzx<8>(a1);  a2 += swzx<8>(a2);  a3 += swzx<8>(a3);
    a0 += swzx<16>(a0); a1 += swzx<16>(a1); a2 += swzx<16>(a2); a3 += swzx<16>(a3);
    a0 += __shfl_xor(a0, 32); a1 += __shfl_xor(a1, 32);
    a2 += __shfl_xor(a2, 32); a3 += __shfl_xor(a3, 32);

    if (p == 0) {   // lanes 0..7 -> one contiguous 64B store
        uint2 o;
        o.x = packbf(a0, a1);
        o.y = packbf(a2, a3);
        *(uint2*)(tmp + bn * 128 + h * 32 + d4 * 4) = o;
    }
}

// ---------------------------------------------------------------------------
// Output GEMM (MFMA, no LDS) + residual: out = tmp @ W12 + b12 + Q.
// ---------------------------------------------------------------------------
__global__ __launch_bounds__(256) void vsa_k_out(
    const ushort* __restrict__ tmp, const ushort* __restrict__ wtp2,
    const float* __restrict__ bias2, const float* __restrict__ Q,
    float* __restrict__ out)
{
    const int lane = threadIdx.x & 63;
    const int wave = blockIdx.x * 4 + (threadIdx.x >> 6);
    const int row0 = wave * 16;
    const int m  = lane & 15;
    const int kg = lane >> 4;

    const ushort* ap = tmp + (size_t)(row0 + m) * 128 + kg * 8;

    f32x4 acc[NF_O];
    #pragma unroll
    for (int f = 0; f < NF_O; ++f) acc[f] = (f32x4){0.f, 0.f, 0.f, 0.f};

    #pragma unroll
    for (int ks = 0; ks < KS; ++ks) {
        short8 af = *(const short8*)(ap + ks * 32);
        const short8* wrow = (const short8*)wtp2 + ks * NF_O * 64 + lane;
        #pragma unroll
        for (int f = 0; f < NF_O; ++f)
            acc[f] = __builtin_amdgcn_mfma_f32_16x16x32_bf16(af, wrow[f * 64], acc[f], 0, 0, 0);
    }

    #pragma unroll
    for (int f = 0; f < NF_O; ++f) {
        const int col = f * 16 + m;
        const float bb = bias2[col];
        #pragma unroll
        for (int r = 0; r < 4; ++r) {
            const int row = row0 + kg * 4 + r;
            out[(size_t)row * 128 + col] = acc[f][r] + bb + Q[(size_t)row * 128 + col];
        }
    }
}

// ---------------------------------------------------------------------------
extern "C" void kernel_launch(void* const* d_in, const int* in_sizes, int n_in,
                              void* d_out, int out_size, void* d_ws, size_t ws_size,
                              hipStream_t stream) {
    const float* Q     = (const float*)d_in[0];
    const float* Wv    = (const float*)d_in[1];
    const float* bv    = (const float*)d_in[2];
    const float* Woff  = (const float*)d_in[3];
    const float* boff  = (const float*)d_in[4];
    const float* Wattn = (const float*)d_in[5];
    const float* battn = (const float*)d_in[6];
    const float* Wout1 = (const float*)d_in[7];
    const float* bout1 = (const float*)d_in[8];
    const float* Wout2 = (const float*)d_in[9];
    const float* bout2 = (const float*)d_in[10];
    float* out = (float*)d_out;

    // Workspace: proj_s f32[BN][96] | biasp[224] | b12[128] |
    //            proj_v bf16[BN][128] | tmp bf16[BN][128] | wtp | wtp2
    float*  proj_s = (float*)d_ws;
    float*  biasp  = proj_s + (size_t)BN * SC;
    float*  bias2  = biasp + 224;
    ushort* proj_v = (ushort*)(bias2 + 128);
    ushort* tmp    = proj_v + (size_t)BN * 128;
    ushort* wtp    = tmp + (size_t)BN * 128;
    ushort* wtp2   = wtp + (size_t)KS * NF_P * 64 * 8;

    constexpr int prep_n = KS * NF_P * 64 + KS * NF_O * 64 + 224 + 128; // 5984
    vsa_k_prep<<<(prep_n + 255) / 256, 256, 0, stream>>>(
        Wv, bv, Woff, boff, Wattn, battn, Wout1, bout1, Wout2, bout2,
        wtp, wtp2, biasp, bias2);
    vsa_k_proj<<<BN / 64, 256, 0, stream>>>(Q, wtp, biasp, proj_v, proj_s);
    vsa_k_sample<<<dim3(Z, X, B), 256, 0, stream>>>(proj_v, proj_s, tmp);
    vsa_k_out<<<BN / 64, 256, 0, stream>>>(tmp, wtp2, bias2, Q, out);
}

// Round 7
// 102.428 us; speedup vs baseline: 2.0074x; 1.2090x over previous
//
#include <hip/hip_runtime.h>
#include <hip/hip_bf16.h>
#include <cstddef>

namespace {
constexpr int B  = 2;
constexpr int Z  = 200;
constexpr int X  = 200;
constexpr int C  = 128;
constexpr int H  = 4;
constexpr int P  = 8;
constexpr int N  = Z * X;       // 40000
constexpr int BN = B * N;       // 80000
constexpr int SC = 96;          // proj_s cols: 64 offsets (f32) + 32 softmax'd weights (f32)
constexpr int NF_P = 14;        // 224/16 output fragments (proj GEMM)
constexpr int NF_O = 8;         // 128/16 output fragments (out GEMM)
constexpr int KS   = 4;         // 128/32 K-steps

typedef __attribute__((ext_vector_type(8))) short short8;
typedef __attribute__((ext_vector_type(4))) float f32x4;

__device__ inline ushort f2bf(float x) {
    __hip_bfloat16 h = __float2bfloat16(x);
    return *reinterpret_cast<ushort*>(&h);
}
__device__ inline float bflo(unsigned u) { return __uint_as_float(u << 16); }
__device__ inline float bfhi(unsigned u) { return __uint_as_float(u & 0xffff0000u); }
__device__ inline unsigned packbf(float a, float b) {
    return (unsigned)f2bf(a) | ((unsigned)f2bf(b) << 16);
}
// single-instruction lane xor-shuffles (BitMode ds_swizzle), within 32-lane groups
template <int MASK>
__device__ inline float swzx(float x) {
    constexpr int pat = (MASK << 10) | 0x1F;
    return __int_as_float(__builtin_amdgcn_ds_swizzle(__float_as_int(x), pat));
}
}

// ---------------------------------------------------------------------------
// Prep: pack weights into MFMA B-fragment order wt[ks][f][lane][8 bf16],
// k = ks*32 + (l>>4)*8 + e, n = f*16 + (l&15). Also folds W12 = Wout1@Wout2,
// biasp[224], b12[128].
// ---------------------------------------------------------------------------
__global__ __launch_bounds__(256) void vsa_k_prep(
    const float* __restrict__ Wv,    const float* __restrict__ bv,
    const float* __restrict__ Woff,  const float* __restrict__ boff,
    const float* __restrict__ Wattn, const float* __restrict__ battn,
    const float* __restrict__ Wout1, const float* __restrict__ bout1,
    const float* __restrict__ Wout2, const float* __restrict__ bout2,
    ushort* __restrict__ wtp, ushort* __restrict__ wtp2,
    float* __restrict__ biasp, float* __restrict__ bias2)
{
    const int u = blockIdx.x * 256 + threadIdx.x;
    constexpr int NP = KS * NF_P * 64;   // 3584
    constexpr int NO = KS * NF_O * 64;   // 2048

    if (u < NP) {
        int ks  = u / (NF_P * 64);
        int rem = u - ks * (NF_P * 64);
        int f = rem >> 6, l = rem & 63;
        int n  = f * 16 + (l & 15);
        int kb = ks * 32 + (l >> 4) * 8;
        float v[8];
        #pragma unroll
        for (int e = 0; e < 8; ++e) {
            int k = kb + e;
            if (n < 128)      v[e] = Wv[k * 128 + n];
            else if (n < 192) v[e] = Woff[k * 64 + (n - 128)];
            else              v[e] = Wattn[k * 32 + (n - 192)];
        }
        unsigned* dst = (unsigned*)(wtp + (size_t)u * 8);
        #pragma unroll
        for (int i = 0; i < 4; ++i) dst[i] = packbf(v[2*i], v[2*i+1]);
    } else if (u < NP + NO) {
        int t   = u - NP;
        int ks  = t / (NF_O * 64);
        int rem = t - ks * (NF_O * 64);
        int f = rem >> 6, l = rem & 63;
        int n  = f * 16 + (l & 15);
        int kb = ks * 32 + (l >> 4) * 8;
        float acc[8] = {0,0,0,0,0,0,0,0};
        for (int j = 0; j < 128; ++j) {
            float w2 = Wout2[j * 128 + n];
            #pragma unroll
            for (int e = 0; e < 8; ++e)
                acc[e] = fmaf(Wout1[(kb + e) * 128 + j], w2, acc[e]);
        }
        unsigned* dst = (unsigned*)(wtp2 + (size_t)t * 8);
        #pragma unroll
        for (int i = 0; i < 4; ++i) dst[i] = packbf(acc[2*i], acc[2*i+1]);
    } else if (u < NP + NO + 224) {
        int c = u - NP - NO;
        float bb;
        if (c < 128)      bb = bv[c];
        else if (c < 192) bb = boff[c - 128];
        else              bb = battn[c - 192];
        biasp[c] = bb;
    } else if (u < NP + NO + 224 + 128) {
        int c = u - NP - NO - 224;
        float acc = bout2[c];
        for (int j = 0; j < 128; ++j)
            acc = fmaf(bout1[j], Wout2[j * 128 + c], acc);
        bias2[c] = acc;
    }
}

// ---------------------------------------------------------------------------
// Fused projection GEMM (MFMA, no LDS) + softmax epilogue.
//   cols 0..127   -> proj_v (bf16 values)
//   cols 128..191 -> proj_s[row][0..63]  (f32 offsets)
//   cols 192..223 -> softmax over each 8-point group (lanes m&7 via xor
//                    ds_swizzle 1/2/4) -> proj_s[row][64..95] (f32 weights)
// ---------------------------------------------------------------------------
__global__ __launch_bounds__(256) void vsa_k_proj(
    const float* __restrict__ Q, const ushort* __restrict__ wtp,
    const float* __restrict__ biasp,
    ushort* __restrict__ proj_v, float* __restrict__ proj_s)
{
    const int lane = threadIdx.x & 63;
    const int wave = blockIdx.x * 4 + (threadIdx.x >> 6);
    const int row0 = wave * 16;
    const int m  = lane & 15;
    const int kg = lane >> 4;

    const float* qp = Q + (size_t)(row0 + m) * 128 + kg * 8;

    f32x4 acc[NF_P];
    #pragma unroll
    for (int f = 0; f < NF_P; ++f) acc[f] = (f32x4){0.f, 0.f, 0.f, 0.f};

    #pragma unroll
    for (int ks = 0; ks < KS; ++ks) {
        float4 a0 = *(const float4*)(qp + ks * 32);
        float4 a1 = *(const float4*)(qp + ks * 32 + 4);
        short8 af;
        af[0] = (short)f2bf(a0.x); af[1] = (short)f2bf(a0.y);
        af[2] = (short)f2bf(a0.z); af[3] = (short)f2bf(a0.w);
        af[4] = (short)f2bf(a1.x); af[5] = (short)f2bf(a1.y);
        af[6] = (short)f2bf(a1.z); af[7] = (short)f2bf(a1.w);
        const short8* wrow = (const short8*)wtp + ks * NF_P * 64 + lane;
        #pragma unroll
        for (int f = 0; f < NF_P; ++f)
            acc[f] = __builtin_amdgcn_mfma_f32_16x16x32_bf16(af, wrow[f * 64], acc[f], 0, 0, 0);
    }

    // values -> bf16
    #pragma unroll
    for (int f = 0; f < 8; ++f) {
        const int col = f * 16 + m;
        const float bb = biasp[col];
        #pragma unroll
        for (int r = 0; r < 4; ++r)
            proj_v[(size_t)(row0 + kg * 4 + r) * 128 + col] = f2bf(acc[f][r] + bb);
    }
    // offsets -> f32
    #pragma unroll
    for (int f = 8; f < 12; ++f) {
        const int col = f * 16 + m;
        const float bb = biasp[col];
        #pragma unroll
        for (int r = 0; r < 4; ++r)
            proj_s[(size_t)(row0 + kg * 4 + r) * SC + (col - 128)] = acc[f][r] + bb;
    }
    // attn logits -> softmax -> f32 weights
    #pragma unroll
    for (int f = 12; f < 14; ++f) {
        const float bb = biasp[f * 16 + m];
        #pragma unroll
        for (int r = 0; r < 4; ++r) {
            float v = acc[f][r] + bb;
            float mx = v;
            mx = fmaxf(mx, swzx<1>(mx));
            mx = fmaxf(mx, swzx<2>(mx));
            mx = fmaxf(mx, swzx<4>(mx));
            float ex = __expf(v - mx);
            float sm = ex;
            sm += swzx<1>(sm); sm += swzx<2>(sm); sm += swzx<4>(sm);
            const float wp = ex / sm;
            proj_s[(size_t)(row0 + kg * 4 + r) * SC + 64 + (f - 12) * 16 + m] = wp;
        }
    }
}

// ---------------------------------------------------------------------------
// Deformable sampling: one wave per (b, n, head-PAIR) — 2 heads/wave halves
// per-head overhead (setup, coord math, addressing, reduce, store).
// Block = 4 waves = 2 pixels x 2 head-pairs. Lane map: half = lane>>5 (head
// within pair), p = bits 2..4 (point), d8 = lane&3 (8 bf16 = 16B quad ->
// 4-lane groups read 64 CONTIGUOUS bytes/corner, same coalescing as r6).
// Reduce over p = ds_swizzle xor 4/8/16, all within 32 lanes (no cross-32).
// Grid (100,200,2). All index math 32-bit. Softmax precomputed in proj.
// ---------------------------------------------------------------------------
__global__ __launch_bounds__(256) void vsa_k_sample(
    const ushort* __restrict__ proj_v, const float* __restrict__ proj_s,
    ushort* __restrict__ tmp)
{
    const int lane  = threadIdx.x & 63;
    const int w     = threadIdx.x >> 6;     // wave 0..3
    const int pixb  = w >> 1;               // pixel within block
    const int hpair = w & 1;                // head pair
    const int h     = hpair * 2 + (lane >> 5);
    const int p     = (lane >> 2) & 7;      // point (bits 2..4)
    const int d8    = lane & 3;             // 16B quad (bits 0..1)

    const int i = blockIdx.x * 2 + pixb;    // gather rows adjacent along i
    const int j = blockIdx.y;
    const int b = blockIdx.z;
    const int bn = b * N + i * X + j;

    const float* srow = proj_s + (size_t)bn * SC;
    const char*  vb   = (const char*)(proj_v + (size_t)b * N * 128);

    // per-point data (broadcast across the 4 d8 lanes of the group)
    const float2 off = *(const float2*)(srow + (h * 8 + p) * 2);
    const float  wp  = srow[64 + h * 8 + p];

    const float ixf = (float)i + off.x;
    const float iyf = (float)j + off.y;
    const float x0f = floorf(ixf), y0f = floorf(iyf);
    const float lx = ixf - x0f, ly = iyf - y0f;
    const int x0 = (int)x0f, y0 = (int)y0f;
    const int x1 = x0 + 1,  y1 = y0 + 1;
    const int xc0 = min(max(x0, 0), X - 1), xc1 = min(max(x1, 0), X - 1);
    const int yc0 = min(max(y0, 0), Z - 1), yc1 = min(max(y1, 0), Z - 1);

    const float wx0 = ((unsigned)x0 < (unsigned)X) ? (1.f - lx) : 0.f;
    const float wx1 = ((unsigned)x1 < (unsigned)X) ? lx : 0.f;
    const float wy0 = (((unsigned)y0 < (unsigned)Z) ? (1.f - ly) : 0.f) * wp;
    const float wy1 = (((unsigned)y1 < (unsigned)Z) ? ly : 0.f) * wp;
    const float w00 = wx0 * wy0, w10 = wx1 * wy0;
    const float w01 = wx0 * wy1, w11 = wx1 * wy1;

    const int rb0 = yc0 * X, rb1 = yc1 * X;
    const int hb  = h * 64 + d8 * 16;      // byte offset in 256B row

    const uint4 c00 = *(const uint4*)(vb + (rb0 + xc0) * 256 + hb);
    const uint4 c10 = *(const uint4*)(vb + (rb0 + xc1) * 256 + hb);
    const uint4 c01 = *(const uint4*)(vb + (rb1 + xc0) * 256 + hb);
    const uint4 c11 = *(const uint4*)(vb + (rb1 + xc1) * 256 + hb);

    float a0 = w00*bflo(c00.x) + w10*bflo(c10.x) + w01*bflo(c01.x) + w11*bflo(c11.x);
    float a1 = w00*bfhi(c00.x) + w10*bfhi(c10.x) + w01*bfhi(c01.x) + w11*bfhi(c11.x);
    float a2 = w00*bflo(c00.y) + w10*bflo(c10.y) + w01*bflo(c01.y) + w11*bflo(c11.y);
    float a3 = w00*bfhi(c00.y) + w10*bfhi(c10.y) + w01*bfhi(c01.y) + w11*bfhi(c11.y);
    float a4 = w00*bflo(c00.z) + w10*bflo(c10.z) + w01*bflo(c01.z) + w11*bflo(c11.z);
    float a5 = w00*bfhi(c00.z) + w10*bfhi(c10.z) + w01*bfhi(c01.z) + w11*bfhi(c11.z);
    float a6 = w00*bflo(c00.w) + w10*bflo(c10.w) + w01*bflo(c01.w) + w11*bflo(c11.w);
    float a7 = w00*bfhi(c00.w) + w10*bfhi(c10.w) + w01*bfhi(c01.w) + w11*bfhi(c11.w);

    // reduce over the 8 points (p = lane bits 2..4), all within 32 lanes
    a0 += swzx<4>(a0);  a1 += swzx<4>(a1);  a2 += swzx<4>(a2);  a3 += swzx<4>(a3);
    a4 += swzx<4>(a4);  a5 += swzx<4>(a5);  a6 += swzx<4>(a6);  a7 += swzx<4>(a7);
    a0 += swzx<8>(a0);  a1 += swzx<8>(a1);  a2 += swzx<8>(a2);  a3 += swzx<8>(a3);
    a4 += swzx<8>(a4);  a5 += swzx<8>(a5);  a6 += swzx<8>(a6);  a7 += swzx<8>(a7);
    a0 += swzx<16>(a0); a1 += swzx<16>(a1); a2 += swzx<16>(a2); a3 += swzx<16>(a3);
    a4 += swzx<16>(a4); a5 += swzx<16>(a5); a6 += swzx<16>(a6); a7 += swzx<16>(a7);

    if (p == 0) {   // lanes {0..3, 32..35}: one contiguous 64B store per head
        uint4 o;
        o.x = packbf(a0, a1);
        o.y = packbf(a2, a3);
        o.z = packbf(a4, a5);
        o.w = packbf(a6, a7);
        *(uint4*)(tmp + bn * 128 + h * 32 + d8 * 8) = o;
    }
}

// ---------------------------------------------------------------------------
// Output GEMM (MFMA, no LDS) + residual: out = tmp @ W12 + b12 + Q.
// ---------------------------------------------------------------------------
__global__ __launch_bounds__(256) void vsa_k_out(
    const ushort* __restrict__ tmp, const ushort* __restrict__ wtp2,
    const float* __restrict__ bias2, const float* __restrict__ Q,
    float* __restrict__ out)
{
    const int lane = threadIdx.x & 63;
    const int wave = blockIdx.x * 4 + (threadIdx.x >> 6);
    const int row0 = wave * 16;
    const int m  = lane & 15;
    const int kg = lane >> 4;

    const ushort* ap = tmp + (size_t)(row0 + m) * 128 + kg * 8;

    f32x4 acc[NF_O];
    #pragma unroll
    for (int f = 0; f < NF_O; ++f) acc[f] = (f32x4){0.f, 0.f, 0.f, 0.f};

    #pragma unroll
    for (int ks = 0; ks < KS; ++ks) {
        short8 af = *(const short8*)(ap + ks * 32);
        const short8* wrow = (const short8*)wtp2 + ks * NF_O * 64 + lane;
        #pragma unroll
        for (int f = 0; f < NF_O; ++f)
            acc[f] = __builtin_amdgcn_mfma_f32_16x16x32_bf16(af, wrow[f * 64], acc[f], 0, 0, 0);
    }

    #pragma unroll
    for (int f = 0; f < NF_O; ++f) {
        const int col = f * 16 + m;
        const float bb = bias2[col];
        #pragma unroll
        for (int r = 0; r < 4; ++r) {
            const int row = row0 + kg * 4 + r;
            out[(size_t)row * 128 + col] = acc[f][r] + bb + Q[(size_t)row * 128 + col];
        }
    }
}

// ---------------------------------------------------------------------------
extern "C" void kernel_launch(void* const* d_in, const int* in_sizes, int n_in,
                              void* d_out, int out_size, void* d_ws, size_t ws_size,
                              hipStream_t stream) {
    const float* Q     = (const float*)d_in[0];
    const float* Wv    = (const float*)d_in[1];
    const float* bv    = (const float*)d_in[2];
    const float* Woff  = (const float*)d_in[3];
    const float* boff  = (const float*)d_in[4];
    const float* Wattn = (const float*)d_in[5];
    const float* battn = (const float*)d_in[6];
    const float* Wout1 = (const float*)d_in[7];
    const float* bout1 = (const float*)d_in[8];
    const float* Wout2 = (const float*)d_in[9];
    const float* bout2 = (const float*)d_in[10];
    float* out = (float*)d_out;

    // Workspace: proj_s f32[BN][96] | biasp[224] | b12[128] |
    //            proj_v bf16[BN][128] | tmp bf16[BN][128] | wtp | wtp2
    float*  proj_s = (float*)d_ws;
    float*  biasp  = proj_s + (size_t)BN * SC;
    float*  bias2  = biasp + 224;
    ushort* proj_v = (ushort*)(bias2 + 128);
    ushort* tmp    = proj_v + (size_t)BN * 128;
    ushort* wtp    = tmp + (size_t)BN * 128;
    ushort* wtp2   = wtp + (size_t)KS * NF_P * 64 * 8;

    constexpr int prep_n = KS * NF_P * 64 + KS * NF_O * 64 + 224 + 128; // 5984
    vsa_k_prep<<<(prep_n + 255) / 256, 256, 0, stream>>>(
        Wv, bv, Woff, boff, Wattn, battn, Wout1, bout1, Wout2, bout2,
        wtp, wtp2, biasp, bias2);
    vsa_k_proj<<<BN / 64, 256, 0, stream>>>(Q, wtp, biasp, proj_v, proj_s);
    vsa_k_sample<<<dim3(Z / 2, X, B), 256, 0, stream>>>(proj_v, proj_s, tmp);
    vsa_k_out<<<BN / 64, 256, 0, stream>>>(tmp, wtp2, bias2, Q, out);
}

// Round 8
// 98.540 us; speedup vs baseline: 2.0866x; 1.0395x over previous
//
#include <hip/hip_runtime.h>
#include <hip/hip_bf16.h>
#include <cstddef>

namespace {
constexpr int B  = 2;
constexpr int Z  = 200;
constexpr int X  = 200;
constexpr int C  = 128;
constexpr int H  = 4;
constexpr int P  = 8;
constexpr int N  = Z * X;       // 40000
constexpr int BN = B * N;       // 80000
constexpr int SC = 96;          // proj_s cols (f16): 64 offsets + 32 softmax'd weights
constexpr int NF_P = 14;        // 224/16 output fragments (proj GEMM)
constexpr int NF_O = 8;         // 128/16 output fragments (out GEMM)
constexpr int KS   = 4;         // 128/32 K-steps

typedef __attribute__((ext_vector_type(8))) short short8;
typedef __attribute__((ext_vector_type(4))) float f32x4;
typedef __attribute__((ext_vector_type(2))) float f32x2;
typedef _Float16 h16x2 __attribute__((ext_vector_type(2)));

__device__ inline ushort f2bf(float x) {
    __hip_bfloat16 h = __float2bfloat16(x);
    return *reinterpret_cast<ushort*>(&h);
}
__device__ inline unsigned packbf(float a, float b) {
    return (unsigned)f2bf(a) | ((unsigned)f2bf(b) << 16);
}
__device__ inline ushort f2h(float x) {
    _Float16 h = (_Float16)x;
    return __builtin_bit_cast(ushort, h);
}
__device__ inline float h1f(ushort u) {
    return (float)__builtin_bit_cast(_Float16, u);
}
__device__ inline float2 h2f2(unsigned u) {
    h16x2 h = __builtin_bit_cast(h16x2, u);
    return make_float2((float)h[0], (float)h[1]);
}
// single-instruction lane xor-shuffles (BitMode ds_swizzle), within 32-lane groups
template <int MASK>
__device__ inline float swzx(float x) {
    constexpr int pat = (MASK << 10) | 0x1F;
    return __int_as_float(__builtin_amdgcn_ds_swizzle(__float_as_int(x), pat));
}
}

// ---------------------------------------------------------------------------
// Prep: pack weights into MFMA B-fragment order wt[ks][f][lane][8 bf16],
// k = ks*32 + (l>>4)*8 + e, n = f*16 + (l&15). Also folds W12 = Wout1@Wout2,
// biasp[224], b12[128].
// ---------------------------------------------------------------------------
__global__ __launch_bounds__(256) void vsa_k_prep(
    const float* __restrict__ Wv,    const float* __restrict__ bv,
    const float* __restrict__ Woff,  const float* __restrict__ boff,
    const float* __restrict__ Wattn, const float* __restrict__ battn,
    const float* __restrict__ Wout1, const float* __restrict__ bout1,
    const float* __restrict__ Wout2, const float* __restrict__ bout2,
    ushort* __restrict__ wtp, ushort* __restrict__ wtp2,
    float* __restrict__ biasp, float* __restrict__ bias2)
{
    const int u = blockIdx.x * 256 + threadIdx.x;
    constexpr int NP = KS * NF_P * 64;   // 3584
    constexpr int NO = KS * NF_O * 64;   // 2048

    if (u < NP) {
        int ks  = u / (NF_P * 64);
        int rem = u - ks * (NF_P * 64);
        int f = rem >> 6, l = rem & 63;
        int n  = f * 16 + (l & 15);
        int kb = ks * 32 + (l >> 4) * 8;
        float v[8];
        #pragma unroll
        for (int e = 0; e < 8; ++e) {
            int k = kb + e;
            if (n < 128)      v[e] = Wv[k * 128 + n];
            else if (n < 192) v[e] = Woff[k * 64 + (n - 128)];
            else              v[e] = Wattn[k * 32 + (n - 192)];
        }
        unsigned* dst = (unsigned*)(wtp + (size_t)u * 8);
        #pragma unroll
        for (int i = 0; i < 4; ++i) dst[i] = packbf(v[2*i], v[2*i+1]);
    } else if (u < NP + NO) {
        int t   = u - NP;
        int ks  = t / (NF_O * 64);
        int rem = t - ks * (NF_O * 64);
        int f = rem >> 6, l = rem & 63;
        int n  = f * 16 + (l & 15);
        int kb = ks * 32 + (l >> 4) * 8;
        float acc[8] = {0,0,0,0,0,0,0,0};
        for (int j = 0; j < 128; ++j) {
            float w2 = Wout2[j * 128 + n];
            #pragma unroll
            for (int e = 0; e < 8; ++e)
                acc[e] = fmaf(Wout1[(kb + e) * 128 + j], w2, acc[e]);
        }
        unsigned* dst = (unsigned*)(wtp2 + (size_t)t * 8);
        #pragma unroll
        for (int i = 0; i < 4; ++i) dst[i] = packbf(acc[2*i], acc[2*i+1]);
    } else if (u < NP + NO + 224) {
        int c = u - NP - NO;
        float bb;
        if (c < 128)      bb = bv[c];
        else if (c < 192) bb = boff[c - 128];
        else              bb = battn[c - 192];
        biasp[c] = bb;
    } else if (u < NP + NO + 224 + 128) {
        int c = u - NP - NO - 224;
        float acc = bout2[c];
        for (int j = 0; j < 128; ++j)
            acc = fmaf(bout1[j], Wout2[j * 128 + c], acc);
        bias2[c] = acc;
    }
}

// ---------------------------------------------------------------------------
// Fused projection GEMM (MFMA, no LDS) + softmax epilogue.
//   cols 0..127   -> proj_v8 (fp8 e4m3 values, HW cvt roundtrip)
//   cols 128..191 -> proj_s16[row][0..63]  (f16 offsets)
//   cols 192..223 -> softmax over each 8-point group (lanes m&7 via xor
//                    ds_swizzle 1/2/4) -> proj_s16[row][64..95] (f16 weights)
// ---------------------------------------------------------------------------
__global__ __launch_bounds__(256) void vsa_k_proj(
    const float* __restrict__ Q, const ushort* __restrict__ wtp,
    const float* __restrict__ biasp,
    unsigned char* __restrict__ proj_v8, ushort* __restrict__ proj_s16)
{
    const int lane = threadIdx.x & 63;
    const int wave = blockIdx.x * 4 + (threadIdx.x >> 6);
    const int row0 = wave * 16;
    const int m  = lane & 15;
    const int kg = lane >> 4;

    const float* qp = Q + (size_t)(row0 + m) * 128 + kg * 8;

    f32x4 acc[NF_P];
    #pragma unroll
    for (int f = 0; f < NF_P; ++f) acc[f] = (f32x4){0.f, 0.f, 0.f, 0.f};

    #pragma unroll
    for (int ks = 0; ks < KS; ++ks) {
        float4 a0 = *(const float4*)(qp + ks * 32);
        float4 a1 = *(const float4*)(qp + ks * 32 + 4);
        short8 af;
        af[0] = (short)f2bf(a0.x); af[1] = (short)f2bf(a0.y);
        af[2] = (short)f2bf(a0.z); af[3] = (short)f2bf(a0.w);
        af[4] = (short)f2bf(a1.x); af[5] = (short)f2bf(a1.y);
        af[6] = (short)f2bf(a1.z); af[7] = (short)f2bf(a1.w);
        const short8* wrow = (const short8*)wtp + ks * NF_P * 64 + lane;
        #pragma unroll
        for (int f = 0; f < NF_P; ++f)
            acc[f] = __builtin_amdgcn_mfma_f32_16x16x32_bf16(af, wrow[f * 64], acc[f], 0, 0, 0);
    }

    // values -> fp8 bytes
    #pragma unroll
    for (int f = 0; f < 8; ++f) {
        const int col = f * 16 + m;
        const float bb = biasp[col];
        #pragma unroll
        for (int r = 0; r < 4; ++r) {
            const float v = acc[f][r] + bb;
            const int pk = __builtin_amdgcn_cvt_pk_fp8_f32(v, v, 0, false);
            proj_v8[(size_t)(row0 + kg * 4 + r) * 128 + col] = (unsigned char)pk;
        }
    }
    // offsets -> f16
    #pragma unroll
    for (int f = 8; f < 12; ++f) {
        const int col = f * 16 + m;
        const float bb = biasp[col];
        #pragma unroll
        for (int r = 0; r < 4; ++r)
            proj_s16[(size_t)(row0 + kg * 4 + r) * SC + (col - 128)] = f2h(acc[f][r] + bb);
    }
    // attn logits -> softmax -> f16 weights
    #pragma unroll
    for (int f = 12; f < 14; ++f) {
        const float bb = biasp[f * 16 + m];
        #pragma unroll
        for (int r = 0; r < 4; ++r) {
            float v = acc[f][r] + bb;
            float mx = v;
            mx = fmaxf(mx, swzx<1>(mx));
            mx = fmaxf(mx, swzx<2>(mx));
            mx = fmaxf(mx, swzx<4>(mx));
            float ex = __expf(v - mx);
            float sm = ex;
            sm += swzx<1>(sm); sm += swzx<2>(sm); sm += swzx<4>(sm);
            const float wp = ex / sm;
            proj_s16[(size_t)(row0 + kg * 4 + r) * SC + 64 + (f - 12) * 16 + m] = f2h(wp);
        }
    }
}

// ---------------------------------------------------------------------------
// Deformable sampling: one wave per (b, n, head-PAIR); 2 pixels x 2 head-pairs
// per block (r7 structure). fp8 values: each 4-lane d8 group reads 32
// CONTIGUOUS bytes per corner (uint2/lane). Reduce = ds_swizzle xor 4/8/16.
// XCD-aware bijective swizzle (1D grid 40000): each XCD owns a contiguous
// 50-column j-slab -> its gather neighborhood (~1.6MB) fits the 4MB L2.
// ---------------------------------------------------------------------------
__global__ __launch_bounds__(256) void vsa_k_sample(
    const unsigned char* __restrict__ proj_v8, const ushort* __restrict__ proj_s16,
    ushort* __restrict__ tmp)
{
    const int lane  = threadIdx.x & 63;
    const int w     = threadIdx.x >> 6;     // wave 0..3
    const int pixb  = w >> 1;               // pixel within block
    const int hpair = w & 1;                // head pair
    const int h     = hpair * 2 + (lane >> 5);
    const int p     = (lane >> 2) & 7;      // point (bits 2..4)
    const int d8    = lane & 3;             // 8-value quad (bits 0..1)

    // XCD-aware bijective swizzle: j becomes the slow dim per XCD slab
    const int orig = blockIdx.x;                      // 0..39999
    const int wg   = (orig & 7) * 5000 + (orig >> 3); // bijective (40000%8==0)
    const int b    = wg / 20000;
    const int r2   = wg - b * 20000;
    const int j    = r2 / 100;
    const int i    = (r2 - j * 100) * 2 + pixb;
    const int bn   = b * N + i * X + j;

    const ushort* srow = proj_s16 + (size_t)bn * SC;
    const unsigned char* vb = proj_v8 + (size_t)b * N * 128;

    // per-point data (broadcast across the 4 d8 lanes of the group)
    const float2 off = h2f2(*(const unsigned*)(srow + (h * 8 + p) * 2));
    const float  wp  = h1f(srow[64 + h * 8 + p]);

    const float ixf = (float)i + off.x;
    const float iyf = (float)j + off.y;
    const float x0f = floorf(ixf), y0f = floorf(iyf);
    const float lx = ixf - x0f, ly = iyf - y0f;
    const int x0 = (int)x0f, y0 = (int)y0f;
    const int x1 = x0 + 1,  y1 = y0 + 1;
    const int xc0 = min(max(x0, 0), X - 1), xc1 = min(max(x1, 0), X - 1);
    const int yc0 = min(max(y0, 0), Z - 1), yc1 = min(max(y1, 0), Z - 1);

    const float wx0 = ((unsigned)x0 < (unsigned)X) ? (1.f - lx) : 0.f;
    const float wx1 = ((unsigned)x1 < (unsigned)X) ? lx : 0.f;
    const float wy0 = (((unsigned)y0 < (unsigned)Z) ? (1.f - ly) : 0.f) * wp;
    const float wy1 = (((unsigned)y1 < (unsigned)Z) ? ly : 0.f) * wp;
    const float w00 = wx0 * wy0, w10 = wx1 * wy0;
    const float w01 = wx0 * wy1, w11 = wx1 * wy1;

    const int rb0 = yc0 * X, rb1 = yc1 * X;
    const int hb  = h * 32 + d8 * 8;       // byte offset in 128B fp8 row

    const uint2 c00 = *(const uint2*)(vb + (rb0 + xc0) * 128 + hb);
    const uint2 c10 = *(const uint2*)(vb + (rb0 + xc1) * 128 + hb);
    const uint2 c01 = *(const uint2*)(vb + (rb1 + xc0) * 128 + hb);
    const uint2 c11 = *(const uint2*)(vb + (rb1 + xc1) * 128 + hb);

    float a0 = 0.f, a1 = 0.f, a2 = 0.f, a3 = 0.f;
    float a4 = 0.f, a5 = 0.f, a6 = 0.f, a7 = 0.f;
    #define VSA_ACC(c, wgt) { \
        f32x2 u0 = __builtin_amdgcn_cvt_pk_f32_fp8((int)(c).x, false); \
        f32x2 u1 = __builtin_amdgcn_cvt_pk_f32_fp8((int)(c).x, true);  \
        f32x2 u2 = __builtin_amdgcn_cvt_pk_f32_fp8((int)(c).y, false); \
        f32x2 u3 = __builtin_amdgcn_cvt_pk_f32_fp8((int)(c).y, true);  \
        a0 = fmaf(wgt, u0.x, a0); a1 = fmaf(wgt, u0.y, a1); \
        a2 = fmaf(wgt, u1.x, a2); a3 = fmaf(wgt, u1.y, a3); \
        a4 = fmaf(wgt, u2.x, a4); a5 = fmaf(wgt, u2.y, a5); \
        a6 = fmaf(wgt, u3.x, a6); a7 = fmaf(wgt, u3.y, a7); }
    VSA_ACC(c00, w00)
    VSA_ACC(c10, w10)
    VSA_ACC(c01, w01)
    VSA_ACC(c11, w11)
    #undef VSA_ACC

    // reduce over the 8 points (p = lane bits 2..4), all within 32 lanes
    a0 += swzx<4>(a0);  a1 += swzx<4>(a1);  a2 += swzx<4>(a2);  a3 += swzx<4>(a3);
    a4 += swzx<4>(a4);  a5 += swzx<4>(a5);  a6 += swzx<4>(a6);  a7 += swzx<4>(a7);
    a0 += swzx<8>(a0);  a1 += swzx<8>(a1);  a2 += swzx<8>(a2);  a3 += swzx<8>(a3);
    a4 += swzx<8>(a4);  a5 += swzx<8>(a5);  a6 += swzx<8>(a6);  a7 += swzx<8>(a7);
    a0 += swzx<16>(a0); a1 += swzx<16>(a1); a2 += swzx<16>(a2); a3 += swzx<16>(a3);
    a4 += swzx<16>(a4); a5 += swzx<16>(a5); a6 += swzx<16>(a6); a7 += swzx<16>(a7);

    if (p == 0) {   // lanes {0..3, 32..35}: one contiguous 64B store per head
        uint4 o;
        o.x = packbf(a0, a1);
        o.y = packbf(a2, a3);
        o.z = packbf(a4, a5);
        o.w = packbf(a6, a7);
        *(uint4*)(tmp + (size_t)bn * 128 + h * 32 + d8 * 8) = o;
    }
}

// ---------------------------------------------------------------------------
// Output GEMM (MFMA, no LDS) + residual: out = tmp @ W12 + b12 + Q.
// ---------------------------------------------------------------------------
__global__ __launch_bounds__(256) void vsa_k_out(
    const ushort* __restrict__ tmp, const ushort* __restrict__ wtp2,
    const float* __restrict__ bias2, const float* __restrict__ Q,
    float* __restrict__ out)
{
    const int lane = threadIdx.x & 63;
    const int wave = blockIdx.x * 4 + (threadIdx.x >> 6);
    const int row0 = wave * 16;
    const int m  = lane & 15;
    const int kg = lane >> 4;

    const ushort* ap = tmp + (size_t)(row0 + m) * 128 + kg * 8;

    f32x4 acc[NF_O];
    #pragma unroll
    for (int f = 0; f < NF_O; ++f) acc[f] = (f32x4){0.f, 0.f, 0.f, 0.f};

    #pragma unroll
    for (int ks = 0; ks < KS; ++ks) {
        short8 af = *(const short8*)(ap + ks * 32);
        const short8* wrow = (const short8*)wtp2 + ks * NF_O * 64 + lane;
        #pragma unroll
        for (int f = 0; f < NF_O; ++f)
            acc[f] = __builtin_amdgcn_mfma_f32_16x16x32_bf16(af, wrow[f * 64], acc[f], 0, 0, 0);
    }

    #pragma unroll
    for (int f = 0; f < NF_O; ++f) {
        const int col = f * 16 + m;
        const float bb = bias2[col];
        #pragma unroll
        for (int r = 0; r < 4; ++r) {
            const int row = row0 + kg * 4 + r;
            out[(size_t)row * 128 + col] = acc[f][r] + bb + Q[(size_t)row * 128 + col];
        }
    }
}

// ---------------------------------------------------------------------------
extern "C" void kernel_launch(void* const* d_in, const int* in_sizes, int n_in,
                              void* d_out, int out_size, void* d_ws, size_t ws_size,
                              hipStream_t stream) {
    const float* Q     = (const float*)d_in[0];
    const float* Wv    = (const float*)d_in[1];
    const float* bv    = (const float*)d_in[2];
    const float* Woff  = (const float*)d_in[3];
    const float* boff  = (const float*)d_in[4];
    const float* Wattn = (const float*)d_in[5];
    const float* battn = (const float*)d_in[6];
    const float* Wout1 = (const float*)d_in[7];
    const float* bout1 = (const float*)d_in[8];
    const float* Wout2 = (const float*)d_in[9];
    const float* bout2 = (const float*)d_in[10];
    float* out = (float*)d_out;

    // Workspace: biasp f32[224] | b12 f32[128] | proj_s16 u16[BN][96] |
    //            proj_v8 u8[BN][128] | tmp bf16[BN][128] | wtp | wtp2
    float*  biasp  = (float*)d_ws;
    float*  bias2  = biasp + 224;
    ushort* proj_s16 = (ushort*)(bias2 + 128);
    unsigned char* proj_v8 = (unsigned char*)(proj_s16 + (size_t)BN * SC);
    ushort* tmp    = (ushort*)(proj_v8 + (size_t)BN * 128);
    ushort* wtp    = tmp + (size_t)BN * 128;
    ushort* wtp2   = wtp + (size_t)KS * NF_P * 64 * 8;

    constexpr int prep_n = KS * NF_P * 64 + KS * NF_O * 64 + 224 + 128; // 5984
    vsa_k_prep<<<(prep_n + 255) / 256, 256, 0, stream>>>(
        Wv, bv, Woff, boff, Wattn, battn, Wout1, bout1, Wout2, bout2,
        wtp, wtp2, biasp, bias2);
    vsa_k_proj<<<BN / 64, 256, 0, stream>>>(Q, wtp, biasp, proj_v8, proj_s16);
    vsa_k_sample<<<dim3((Z / 2) * X * B), 256, 0, stream>>>(proj_v8, proj_s16, tmp);
    vsa_k_out<<<BN / 64, 256, 0, stream>>>(tmp, wtp2, bias2, Q, out);
}

// Round 10
// 94.811 us; speedup vs baseline: 2.1687x; 1.0393x over previous
//
#include <hip/hip_runtime.h>
#include <hip/hip_bf16.h>
#include <cstddef>

namespace {
constexpr int B  = 2;
constexpr int Z  = 200;
constexpr int X  = 200;
constexpr int C  = 128;
constexpr int H  = 4;
constexpr int P  = 8;
constexpr int N  = Z * X;       // 40000
constexpr int BN = B * N;       // 80000
constexpr int SC = 128;         // proj_s cols (f16): [hp][{offx,offy,wp,pad}]
constexpr int NF_P = 14;        // 224/16 output fragments (proj GEMM)
constexpr int NF_O = 8;         // 128/16 output fragments (out GEMM)
constexpr int KS   = 4;         // 128/32 K-steps

typedef __attribute__((ext_vector_type(8))) short short8;
typedef __attribute__((ext_vector_type(4))) float f32x4;
typedef _Float16 h16x2 __attribute__((ext_vector_type(2)));

__device__ inline ushort f2bf(float x) {
    __hip_bfloat16 h = __float2bfloat16(x);
    return *reinterpret_cast<ushort*>(&h);
}
__device__ inline unsigned packbf(float a, float b) {
    return (unsigned)f2bf(a) | ((unsigned)f2bf(b) << 16);
}
__device__ inline ushort f2h(float x) {
    _Float16 h = (_Float16)x;
    return __builtin_bit_cast(ushort, h);
}
__device__ inline float h1f(ushort u) {
    return (float)__builtin_bit_cast(_Float16, u);
}
__device__ inline float2 h2f2(unsigned u) {
    h16x2 h = __builtin_bit_cast(h16x2, u);
    return make_float2((float)h[0], (float)h[1]);
}
__device__ inline unsigned packh(float a, float b) {
    return (unsigned)f2h(a) | ((unsigned)f2h(b) << 16);
}
// packed f32->f16x2 convert (v_cvt_pkrtz_f16_f32), bit-cast to our h16x2
__device__ inline h16x2 pkrtz(float a, float b) {
    return __builtin_bit_cast(h16x2, __builtin_amdgcn_cvt_pkrtz(a, b));
}
// single-instruction lane xor-shuffles (BitMode ds_swizzle), within 32-lane groups
template <int MASK>
__device__ inline float swzx(float x) {
    constexpr int pat = (MASK << 10) | 0x1F;
    return __int_as_float(__builtin_amdgcn_ds_swizzle(__float_as_int(x), pat));
}
template <int MASK>
__device__ inline h16x2 swzh(h16x2 x) {
    constexpr int pat = (MASK << 10) | 0x1F;
    int t = __builtin_amdgcn_ds_swizzle(__builtin_bit_cast(int, x), pat);
    return __builtin_bit_cast(h16x2, t);
}
}

// ---------------------------------------------------------------------------
// Prep: pack weights into MFMA B-fragment order wt[ks][f][lane][8 elems],
// k = ks*32 + (l>>4)*8 + e, n = f*16 + (l&15). wtp = bf16 (proj GEMM),
// wtp2 = f16 (out GEMM, W12 = Wout1@Wout2). Also biasp[224], b12[128].
// ---------------------------------------------------------------------------
__global__ __launch_bounds__(256) void vsa_k_prep(
    const float* __restrict__ Wv,    const float* __restrict__ bv,
    const float* __restrict__ Woff,  const float* __restrict__ boff,
    const float* __restrict__ Wattn, const float* __restrict__ battn,
    const float* __restrict__ Wout1, const float* __restrict__ bout1,
    const float* __restrict__ Wout2, const float* __restrict__ bout2,
    ushort* __restrict__ wtp, ushort* __restrict__ wtp2,
    float* __restrict__ biasp, float* __restrict__ bias2)
{
    const int u = blockIdx.x * 256 + threadIdx.x;
    constexpr int NP = KS * NF_P * 64;   // 3584
    constexpr int NO = KS * NF_O * 64;   // 2048

    if (u < NP) {
        int ks  = u / (NF_P * 64);
        int rem = u - ks * (NF_P * 64);
        int f = rem >> 6, l = rem & 63;
        int n  = f * 16 + (l & 15);
        int kb = ks * 32 + (l >> 4) * 8;
        float v[8];
        #pragma unroll
        for (int e = 0; e < 8; ++e) {
            int k = kb + e;
            if (n < 128)      v[e] = Wv[k * 128 + n];
            else if (n < 192) v[e] = Woff[k * 64 + (n - 128)];
            else              v[e] = Wattn[k * 32 + (n - 192)];
        }
        unsigned* dst = (unsigned*)(wtp + (size_t)u * 8);
        #pragma unroll
        for (int i = 0; i < 4; ++i) dst[i] = packbf(v[2*i], v[2*i+1]);
    } else if (u < NP + NO) {
        int t   = u - NP;
        int ks  = t / (NF_O * 64);
        int rem = t - ks * (NF_O * 64);
        int f = rem >> 6, l = rem & 63;
        int n  = f * 16 + (l & 15);
        int kb = ks * 32 + (l >> 4) * 8;
        float acc[8] = {0,0,0,0,0,0,0,0};
        for (int j = 0; j < 128; ++j) {
            float w2 = Wout2[j * 128 + n];
            #pragma unroll
            for (int e = 0; e < 8; ++e)
                acc[e] = fmaf(Wout1[(kb + e) * 128 + j], w2, acc[e]);
        }
        unsigned* dst = (unsigned*)(wtp2 + (size_t)t * 8);
        #pragma unroll
        for (int i = 0; i < 4; ++i) dst[i] = packh(acc[2*i], acc[2*i+1]);
    } else if (u < NP + NO + 224) {
        int c = u - NP - NO;
        float bb;
        if (c < 128)      bb = bv[c];
        else if (c < 192) bb = boff[c - 128];
        else              bb = battn[c - 192];
        biasp[c] = bb;
    } else if (u < NP + NO + 224 + 128) {
        int c = u - NP - NO - 224;
        float acc = bout2[c];
        for (int j = 0; j < 128; ++j)
            acc = fmaf(bout1[j], Wout2[j * 128 + c], acc);
        bias2[c] = acc;
    }
}

// ---------------------------------------------------------------------------
// Fused projection GEMM (MFMA, no LDS) + softmax epilogue.
//   cols 0..127   -> proj_v16 (f16 values)
//   cols 128..191 -> proj_s16[row][hp*4 + {0,1}] (f16 offsets)
//   cols 192..223 -> softmax over each 8-point group (lanes m&7 via xor
//                    ds_swizzle 1/2/4) -> proj_s16[row][hp*4 + 2] (f16 wp)
// ---------------------------------------------------------------------------
__global__ __launch_bounds__(256) void vsa_k_proj(
    const float* __restrict__ Q, const ushort* __restrict__ wtp,
    const float* __restrict__ biasp,
    ushort* __restrict__ proj_v16, ushort* __restrict__ proj_s16)
{
    const int lane = threadIdx.x & 63;
    const int wave = blockIdx.x * 4 + (threadIdx.x >> 6);
    const int row0 = wave * 16;
    const int m  = lane & 15;
    const int kg = lane >> 4;

    const float* qp = Q + (size_t)(row0 + m) * 128 + kg * 8;

    f32x4 acc[NF_P];
    #pragma unroll
    for (int f = 0; f < NF_P; ++f) acc[f] = (f32x4){0.f, 0.f, 0.f, 0.f};

    #pragma unroll
    for (int ks = 0; ks < KS; ++ks) {
        float4 a0 = *(const float4*)(qp + ks * 32);
        float4 a1 = *(const float4*)(qp + ks * 32 + 4);
        short8 af;
        af[0] = (short)f2bf(a0.x); af[1] = (short)f2bf(a0.y);
        af[2] = (short)f2bf(a0.z); af[3] = (short)f2bf(a0.w);
        af[4] = (short)f2bf(a1.x); af[5] = (short)f2bf(a1.y);
        af[6] = (short)f2bf(a1.z); af[7] = (short)f2bf(a1.w);
        const short8* wrow = (const short8*)wtp + ks * NF_P * 64 + lane;
        #pragma unroll
        for (int f = 0; f < NF_P; ++f)
            acc[f] = __builtin_amdgcn_mfma_f32_16x16x32_bf16(af, wrow[f * 64], acc[f], 0, 0, 0);
    }

    // values -> f16
    #pragma unroll
    for (int f = 0; f < 8; ++f) {
        const int col = f * 16 + m;
        const float bb = biasp[col];
        #pragma unroll
        for (int r = 0; r < 4; ++r)
            proj_v16[(size_t)(row0 + kg * 4 + r) * 128 + col] = f2h(acc[f][r] + bb);
    }
    // offsets -> f16 at [hp*4 + comp]
    #pragma unroll
    for (int f = 8; f < 12; ++f) {
        const int col = f * 16 + m;
        const float bb = biasp[col];
        const int c  = col - 128;          // 0..63
        const int hp = c >> 1, comp = c & 1;
        #pragma unroll
        for (int r = 0; r < 4; ++r)
            proj_s16[(size_t)(row0 + kg * 4 + r) * SC + hp * 4 + comp] = f2h(acc[f][r] + bb);
    }
    // attn logits -> softmax -> f16 weights at [hp*4 + 2]
    #pragma unroll
    for (int f = 12; f < 14; ++f) {
        const float bb = biasp[f * 16 + m];
        const int hp = (f - 12) * 16 + m;  // 0..31
        #pragma unroll
        for (int r = 0; r < 4; ++r) {
            float v = acc[f][r] + bb;
            float mx = v;
            mx = fmaxf(mx, swzx<1>(mx));
            mx = fmaxf(mx, swzx<2>(mx));
            mx = fmaxf(mx, swzx<4>(mx));
            float ex = __expf(v - mx);
            float sm = ex;
            sm += swzx<1>(sm); sm += swzx<2>(sm); sm += swzx<4>(sm);
            const float wp = ex / sm;
            proj_s16[(size_t)(row0 + kg * 4 + r) * SC + hp * 4 + 2] = f2h(wp);
        }
    }
}

// ---------------------------------------------------------------------------
// Deformable sampling: one wave per (b, n, head-PAIR); 2 pixels x 2 head-pairs
// per block. f16 values: each 4-lane d8 group reads 64 CONTIGUOUS bytes per
// corner (uint4/lane). Packed-f16 math: 4 cvt_pkrtz + 16 pk_fma per point;
// reduce = 12 swizzle + 12 pk_add; accumulators stored DIRECTLY (tmp is f16).
// XCD-aware bijective swizzle (1D grid 40000): contiguous j-slab per XCD.
// ---------------------------------------------------------------------------
__global__ __launch_bounds__(256) void vsa_k_sample(
    const ushort* __restrict__ proj_v16, const ushort* __restrict__ proj_s16,
    ushort* __restrict__ tmp)
{
    const int lane  = threadIdx.x & 63;
    const int w     = threadIdx.x >> 6;     // wave 0..3
    const int pixb  = w >> 1;               // pixel within block
    const int hpair = w & 1;                // head pair
    const int h     = hpair * 2 + (lane >> 5);
    const int p     = (lane >> 2) & 7;      // point (bits 2..4)
    const int d8    = lane & 3;             // 8-value quad (bits 0..1)

    // XCD-aware bijective swizzle: j becomes the slow dim per XCD slab
    const int orig = blockIdx.x;                      // 0..39999
    const int wg   = (orig & 7) * 5000 + (orig >> 3); // bijective (40000%8==0)
    const int b    = wg / 20000;
    const int r2   = wg - b * 20000;
    const int j    = r2 / 100;
    const int i    = (r2 - j * 100) * 2 + pixb;
    const int bn   = b * N + i * X + j;

    // per-point data: one uint2 = {offx, offy, wp, pad} f16
    const uint2 ow = *(const uint2*)(proj_s16 + (size_t)bn * SC + (h * 8 + p) * 4);
    const float2 off = h2f2(ow.x);
    const float  wp  = h1f((ushort)(ow.y & 0xffff));

    const float ixf = (float)i + off.x;
    const float iyf = (float)j + off.y;
    const float x0f = floorf(ixf), y0f = floorf(iyf);
    const float lx = ixf - x0f, ly = iyf - y0f;
    const int x0 = (int)x0f, y0 = (int)y0f;
    const int x1 = x0 + 1,  y1 = y0 + 1;
    const int xc0 = min(max(x0, 0), X - 1), xc1 = min(max(x1, 0), X - 1);
    const int yc0 = min(max(y0, 0), Z - 1), yc1 = min(max(y1, 0), Z - 1);

    const float wx0 = ((unsigned)x0 < (unsigned)X) ? (1.f - lx) : 0.f;
    const float wx1 = ((unsigned)x1 < (unsigned)X) ? lx : 0.f;
    const float wy0 = (((unsigned)y0 < (unsigned)Z) ? (1.f - ly) : 0.f) * wp;
    const float wy1 = (((unsigned)y1 < (unsigned)Z) ? ly : 0.f) * wp;

    // packed f16 corner weights (broadcast to both halves)
    const h16x2 w00p = pkrtz(wx0 * wy0, wx0 * wy0);
    const h16x2 w10p = pkrtz(wx1 * wy0, wx1 * wy0);
    const h16x2 w01p = pkrtz(wx0 * wy1, wx0 * wy1);
    const h16x2 w11p = pkrtz(wx1 * wy1, wx1 * wy1);

    const ushort* vb = proj_v16 + (size_t)b * N * 128;
    const int rb0 = yc0 * X, rb1 = yc1 * X;
    const int hb  = h * 32 + d8 * 8;       // f16-elem offset in 128-elem row

    const uint4 c00 = *(const uint4*)(vb + (size_t)(rb0 + xc0) * 128 + hb);
    const uint4 c10 = *(const uint4*)(vb + (size_t)(rb0 + xc1) * 128 + hb);
    const uint4 c01 = *(const uint4*)(vb + (size_t)(rb1 + xc0) * 128 + hb);
    const uint4 c11 = *(const uint4*)(vb + (size_t)(rb1 + xc1) * 128 + hb);

    h16x2 a0 = (h16x2)0, a1 = (h16x2)0, a2 = (h16x2)0, a3 = (h16x2)0;
    #define VSA_ACC(c, wpk) { \
        a0 = __builtin_elementwise_fma(__builtin_bit_cast(h16x2, (c).x), wpk, a0); \
        a1 = __builtin_elementwise_fma(__builtin_bit_cast(h16x2, (c).y), wpk, a1); \
        a2 = __builtin_elementwise_fma(__builtin_bit_cast(h16x2, (c).z), wpk, a2); \
        a3 = __builtin_elementwise_fma(__builtin_bit_cast(h16x2, (c).w), wpk, a3); }
    VSA_ACC(c00, w00p)
    VSA_ACC(c10, w10p)
    VSA_ACC(c01, w01p)
    VSA_ACC(c11, w11p)
    #undef VSA_ACC

    // reduce over the 8 points (p = lane bits 2..4), packed adds, within 32 lanes
    a0 += swzh<4>(a0);  a1 += swzh<4>(a1);  a2 += swzh<4>(a2);  a3 += swzh<4>(a3);
    a0 += swzh<8>(a0);  a1 += swzh<8>(a1);  a2 += swzh<8>(a2);  a3 += swzh<8>(a3);
    a0 += swzh<16>(a0); a1 += swzh<16>(a1); a2 += swzh<16>(a2); a3 += swzh<16>(a3);

    if (p == 0) {   // lanes {0..3, 32..35}: store accumulators directly (f16)
        uint4 o;
        o.x = __builtin_bit_cast(unsigned, a0);
        o.y = __builtin_bit_cast(unsigned, a1);
        o.z = __builtin_bit_cast(unsigned, a2);
        o.w = __builtin_bit_cast(unsigned, a3);
        *(uint4*)(tmp + (size_t)bn * 128 + h * 32 + d8 * 8) = o;
    }
}

// ---------------------------------------------------------------------------
// Output GEMM (f16 MFMA, no LDS) + residual: out = tmp @ W12 + b12 + Q.
// ---------------------------------------------------------------------------
__global__ __launch_bounds__(256) void vsa_k_out(
    const ushort* __restrict__ tmp, const ushort* __restrict__ wtp2,
    const float* __restrict__ bias2, const float* __restrict__ Q,
    float* __restrict__ out)
{
    const int lane = threadIdx.x & 63;
    const int wave = blockIdx.x * 4 + (threadIdx.x >> 6);
    const int row0 = wave * 16;
    const int m  = lane & 15;
    const int kg = lane >> 4;

    const ushort* ap = tmp + (size_t)(row0 + m) * 128 + kg * 8;

    f32x4 acc[NF_O];
    #pragma unroll
    for (int f = 0; f < NF_O; ++f) acc[f] = (f32x4){0.f, 0.f, 0.f, 0.f};

    #pragma unroll
    for (int ks = 0; ks < KS; ++ks) {
        short8 af = *(const short8*)(ap + ks * 32);
        const short8* wrow = (const short8*)wtp2 + ks * NF_O * 64 + lane;
        #pragma unroll
        for (int f = 0; f < NF_O; ++f)
            acc[f] = __builtin_amdgcn_mfma_f32_16x16x32_f16(af, wrow[f * 64], acc[f], 0, 0, 0);
    }

    #pragma unroll
    for (int f = 0; f < NF_O; ++f) {
        const int col = f * 16 + m;
        const float bb = bias2[col];
        #pragma unroll
        for (int r = 0; r < 4; ++r) {
            const int row = row0 + kg * 4 + r;
            out[(size_t)row * 128 + col] = acc[f][r] + bb + Q[(size_t)row * 128 + col];
        }
    }
}

// ---------------------------------------------------------------------------
extern "C" void kernel_launch(void* const* d_in, const int* in_sizes, int n_in,
                              void* d_out, int out_size, void* d_ws, size_t ws_size,
                              hipStream_t stream) {
    const float* Q     = (const float*)d_in[0];
    const float* Wv    = (const float*)d_in[1];
    const float* bv    = (const float*)d_in[2];
    const float* Woff  = (const float*)d_in[3];
    const float* boff  = (const float*)d_in[4];
    const float* Wattn = (const float*)d_in[5];
    const float* battn = (const float*)d_in[6];
    const float* Wout1 = (const float*)d_in[7];
    const float* bout1 = (const float*)d_in[8];
    const float* Wout2 = (const float*)d_in[9];
    const float* bout2 = (const float*)d_in[10];
    float* out = (float*)d_out;

    // Workspace: biasp f32[224] | b12 f32[128] | proj_s16 u16[BN][128] |
    //            proj_v16 u16[BN][128] | tmp f16[BN][128] | wtp | wtp2
    float*  biasp  = (float*)d_ws;
    float*  bias2  = biasp + 224;
    ushort* proj_s16 = (ushort*)(bias2 + 128);
    ushort* proj_v16 = proj_s16 + (size_t)BN * SC;
    ushort* tmp    = proj_v16 + (size_t)BN * 128;
    ushort* wtp    = tmp + (size_t)BN * 128;
    ushort* wtp2   = wtp + (size_t)KS * NF_P * 64 * 8;

    constexpr int prep_n = KS * NF_P * 64 + KS * NF_O * 64 + 224 + 128; // 5984
    vsa_k_prep<<<(prep_n + 255) / 256, 256, 0, stream>>>(
        Wv, bv, Woff, boff, Wattn, battn, Wout1, bout1, Wout2, bout2,
        wtp, wtp2, biasp, bias2);
    vsa_k_proj<<<BN / 64, 256, 0, stream>>>(Q, wtp, biasp, proj_v16, proj_s16);
    vsa_k_sample<<<dim3((Z / 2) * X * B), 256, 0, stream>>>(proj_v16, proj_s16, tmp);
    vsa_k_out<<<BN / 64, 256, 0, stream>>>(tmp, wtp2, bias2, Q, out);
}